// Round 1
// baseline (386.043 us; speedup 1.0000x reference)
//
#include <hip/hip_runtime.h>

// Problem constants
#define BB 8
#define CI 32
#define CO 32
#define HH 256
#define WW 256
#define HF 64
#define KX 32   // kept kx modes
#define NJ 64   // kept ky modes (0..31, 224..255)

__device__ __constant__ float PI2 = 6.28318530717958647692f;

// ---------------------------------------------------------------------------
// Stage W: spectral weights  WC[s][m1][m2][i][o] (complex) =
//          dot(weights[i,o,s,:], mlp_w[(m1*32+m2)*2+c, :])
// ---------------------------------------------------------------------------
__global__ void kweights(const float* __restrict__ wts, const float* __restrict__ mlp,
                         float* __restrict__ WC) {
    int mode = blockIdx.x;            // s*1024 + m1*32 + m2
    int m1m2 = mode & 1023;
    int s = mode >> 10;
    __shared__ float rowr[HF];
    __shared__ float rowi[HF];
    int t = threadIdx.x;
    if (t < HF)           rowr[t]      = mlp[(m1m2 * 2 + 0) * HF + t];
    else if (t < 2 * HF)  rowi[t - HF] = mlp[(m1m2 * 2 + 1) * HF + (t - HF)];
    __syncthreads();
    int o = t & 31, i0 = t >> 5;
    #pragma unroll
    for (int ii = 0; ii < 4; ii++) {
        int i = i0 * 4 + ii;
        const float* wp = wts + ((i * CO + o) * 2 + s) * HF;
        float ar = 0.f, ai = 0.f;
        #pragma unroll 8
        for (int k = 0; k < HF; k++) {
            float wv = wp[k];
            ar = fmaf(wv, rowr[k], ar);
            ai = fmaf(wv, rowi[k], ai);
        }
        ((float2*)WC)[(mode * CI + i) * CO + o] = make_float2(ar, ai);
    }
}

// ---------------------------------------------------------------------------
// Stage 1: forward DFT over w.  Xc[b][i][h][kx] = sum_w x[b,i,h,w] e^{-2pi i w kx/256}
// block = 8 rows of x, threads (kx:32, r:8)
// ---------------------------------------------------------------------------
__global__ void kfwd_w(const float* __restrict__ x, float* __restrict__ Xc) {
    __shared__ float xs[8][WW];
    int t = threadIdx.x;
    int row0 = blockIdx.x * 8;                  // row = (b*CI+i)*H + h
    const float4* xg4 = (const float4*)(x + (size_t)row0 * WW);
    float4* xs4 = (float4*)&xs[0][0];
    #pragma unroll
    for (int idx = t; idx < 8 * WW / 4; idx += 256) xs4[idx] = xg4[idx];
    __syncthreads();
    int kx = t & 31, r = t >> 5;
    float sn, cs;
    sincosf(-PI2 * (float)kx / 256.0f, &sn, &cs);
    float tr = 1.f, ti = 0.f, ar = 0.f, ai = 0.f;
    #pragma unroll 8
    for (int w = 0; w < WW; w++) {
        float xv = xs[r][w];
        ar = fmaf(xv, tr, ar);
        ai = fmaf(xv, ti, ai);
        float ntr = tr * cs - ti * sn;
        ti = fmaf(tr, sn, ti * cs);
        tr = ntr;
    }
    ((float2*)Xc)[(size_t)(row0 + r) * KX + kx] = make_float2(ar, ai);
}

// ---------------------------------------------------------------------------
// Stage 2: forward DFT over h (64 kept ky).  F[b][i][j][kx], complex.
// block per (b,i): LDS = full slab Xc[b][i][256][32] (64 KB)
// threads (j:64, kxg:4), each thread does 8 kx
// ---------------------------------------------------------------------------
__global__ void kfwd_h(const float* __restrict__ Xc, float* __restrict__ F) {
    __shared__ float2 xs[HH][KX];   // 64 KB
    int t = threadIdx.x;
    int bi = blockIdx.x;            // 0..255
    const float2* xg = ((const float2*)Xc) + (size_t)bi * HH * KX;
    for (int idx = t; idx < HH * KX; idx += 256) ((float2*)xs)[idx] = xg[idx];
    __syncthreads();
    int j = t & 63, kxg = t >> 6;
    int ky = (j < 32) ? j : (192 + j);          // 224..255 for j>=32
    float sn, cs;
    sincosf(-PI2 * (float)ky / 256.0f, &sn, &cs);
    float tr = 1.f, ti = 0.f;
    float accr[8], acci[8];
    #pragma unroll
    for (int q = 0; q < 8; q++) { accr[q] = 0.f; acci[q] = 0.f; }
    for (int h = 0; h < HH; h++) {
        #pragma unroll
        for (int q = 0; q < 8; q++) {
            float2 v = xs[h][kxg * 8 + q];
            accr[q] = fmaf(v.x, tr, accr[q]);
            accr[q] = fmaf(-v.y, ti, accr[q]);
            acci[q] = fmaf(v.x, ti, acci[q]);
            acci[q] = fmaf(v.y, tr, acci[q]);
        }
        float ntr = tr * cs - ti * sn;
        ti = fmaf(tr, sn, ti * cs);
        tr = ntr;
    }
    float2* Fo = ((float2*)F) + ((size_t)bi * NJ + j) * KX + kxg * 8;
    #pragma unroll
    for (int q = 0; q < 8; q++) Fo[q] = make_float2(accr[q], acci[q]);
}

// ---------------------------------------------------------------------------
// Stage 3: mode mixing.  OM[b][o][j][kx] = (1/65536) * mod[b,mode] *
//                        sum_i F[b][i][j][kx] * WC[s][m1][m2][i][o]
// block per (j,kx); threads (b:8, o:32)
// ---------------------------------------------------------------------------
__global__ void kmodes(const float* __restrict__ F, const float* __restrict__ WC,
                       const float* __restrict__ mod1, const float* __restrict__ mod2,
                       float* __restrict__ OM) {
    int m = blockIdx.x;             // j*32 + kx
    int j = m >> 5, kx = m & 31;
    int s = j >> 5;
    int m1 = j & 31, m2 = kx;
    __shared__ float2 fs[BB][CI];
    __shared__ float2 wcs[CI][CO];
    int t = threadIdx.x;
    {
        int b = t >> 5, i = t & 31;
        fs[b][i] = ((const float2*)F)[((size_t)(b * CI + i) * NJ + j) * KX + kx];
    }
    {
        const float2* wg = ((const float2*)WC) + (size_t)(s * 1024 + m1 * 32 + m2) * CI * CO;
        #pragma unroll
        for (int idx = t; idx < CI * CO; idx += 256) ((float2*)wcs)[idx] = wg[idx];
    }
    __syncthreads();
    int b = t >> 5, o = t & 31;
    float ar = 0.f, ai = 0.f;
    #pragma unroll 8
    for (int i = 0; i < CI; i++) {
        float2 f = fs[b][i];
        float2 w = wcs[i][o];
        ar = fmaf(f.x, w.x, ar);
        ar = fmaf(-f.y, w.y, ar);
        ai = fmaf(f.x, w.y, ai);
        ai = fmaf(f.y, w.x, ai);
    }
    const float* mp = (s == 0) ? mod1 : mod2;
    float mr = mp[(b * 1024 + m1 * 32 + m2) * 2 + 0];
    float mi = mp[(b * 1024 + m1 * 32 + m2) * 2 + 1];
    const float scale = 1.0f / 65536.0f;
    float outr = (ar * mr - ai * mi) * scale;
    float outi = (ar * mi + ai * mr) * scale;
    ((float2*)OM)[((size_t)(b * CO + o) * NJ + j) * KX + kx] = make_float2(outr, outi);
}

// ---------------------------------------------------------------------------
// Stage 4: inverse DFT over h.  G[b][o][h][kx] = sum_j OM[b][o][j][kx] e^{+2pi i ky_j h/256}
// block per (b,o); thread = h; 32 complex accumulators per thread
// ---------------------------------------------------------------------------
__global__ void kinv_h(const float* __restrict__ OM, float* __restrict__ G) {
    __shared__ float2 os[NJ][KX];   // 16 KB
    int bo = blockIdx.x;            // 0..255
    int t = threadIdx.x;
    const float2* og = ((const float2*)OM) + (size_t)bo * NJ * KX;
    for (int idx = t; idx < NJ * KX; idx += 256) ((float2*)os)[idx] = og[idx];
    __syncthreads();
    int h = t;
    float sn, cs;
    sincosf(PI2 * (float)h / 256.0f, &sn, &cs);
    float tr = 1.f, ti = 0.f;
    float accr[KX], acci[KX];
    #pragma unroll
    for (int kx = 0; kx < KX; kx++) { accr[kx] = 0.f; acci[kx] = 0.f; }
    for (int jj = 0; jj < NJ; jj++) {
        if (jj == 32) ti = -ti;     // state e^{2pi i 32h/256} -> conj = e^{2pi i 224h/256}
        #pragma unroll
        for (int kx = 0; kx < KX; kx++) {
            float2 v = os[jj][kx];
            accr[kx] = fmaf(v.x, tr, accr[kx]);
            accr[kx] = fmaf(-v.y, ti, accr[kx]);
            acci[kx] = fmaf(v.x, ti, acci[kx]);
            acci[kx] = fmaf(v.y, tr, acci[kx]);
        }
        float ntr = tr * cs - ti * sn;
        ti = fmaf(tr, sn, ti * cs);
        tr = ntr;
    }
    float2* Go = ((float2*)G) + ((size_t)bo * HH + h) * KX;
    #pragma unroll
    for (int kx = 0; kx < KX; kx++) Go[kx] = make_float2(accr[kx], acci[kx]);
}

// ---------------------------------------------------------------------------
// Stage 5: inverse real DFT over w (pocketfft c2r: imag of bin 0 dropped).
// y[row][w] = G[row][0].re + 2*sum_{kx=1}^{31} (Gr cos - Gi sin), phi = 2pi kx w/256
// block = 8 rows (row = (b*CO+o)*H + h), threads (wl:32, r:8), each does 8 w
// ---------------------------------------------------------------------------
__global__ void kinv_w(const float* __restrict__ G, float* __restrict__ y) {
    __shared__ float2 gs[8][KX];    // 2 KB
    int t = threadIdx.x;
    int row0 = blockIdx.x * 8;
    const float2* gg = ((const float2*)G) + (size_t)row0 * KX;
    for (int idx = t; idx < 8 * KX; idx += 256) ((float2*)gs)[idx] = gg[idx];
    __syncthreads();
    int wl = t & 31, r = t >> 5;
    float accr[8], trq[8], tiq[8], csq[8], snq[8];
    #pragma unroll
    for (int q = 0; q < 8; q++) {
        int w = wl + 32 * q;
        sincosf(PI2 * (float)w / 256.0f, &snq[q], &csq[q]);
        trq[q] = csq[q];            // state at kx=1
        tiq[q] = snq[q];
        accr[q] = 0.5f * gs[r][0].x;
    }
    for (int kx = 1; kx < KX; kx++) {
        float2 v = gs[r][kx];
        #pragma unroll
        for (int q = 0; q < 8; q++) {
            accr[q] = fmaf(v.x, trq[q], accr[q]);
            accr[q] = fmaf(-v.y, tiq[q], accr[q]);
            float ntr = trq[q] * csq[q] - tiq[q] * snq[q];
            tiq[q] = fmaf(trq[q], snq[q], tiq[q] * csq[q]);
            trq[q] = ntr;
        }
    }
    float* yo = y + (size_t)row0 * WW;
    #pragma unroll
    for (int q = 0; q < 8; q++) yo[r * WW + wl + 32 * q] = 2.0f * accr[q];
}

// ---------------------------------------------------------------------------
extern "C" void kernel_launch(void* const* d_in, const int* in_sizes, int n_in,
                              void* d_out, int out_size, void* d_ws, size_t ws_size,
                              hipStream_t stream) {
    const float* x    = (const float*)d_in[0];
    const float* mod1 = (const float*)d_in[1];
    const float* mod2 = (const float*)d_in[2];
    const float* wts  = (const float*)d_in[3];
    const float* mlp  = (const float*)d_in[4];
    float* y = (float*)d_out;

    float* ws = (float*)d_ws;
    // workspace layout (floats)
    float* Xc = ws;                         // 8*32*256*32*2  = 4,194,304
    float* F  = Xc + 4194304;               // 8*32*64*32*2   = 1,048,576
    float* WC = F  + 1048576;               // 2*32*32*32*32*2= 4,194,304
    float* OM = WC + 4194304;               // 8*32*64*32*2   = 1,048,576
    float* G  = OM + 1048576;               // 8*32*256*32*2  = 4,194,304
    // total 14,680,064 floats = 56 MB

    kweights<<<dim3(2048), dim3(256), 0, stream>>>(wts, mlp, WC);
    kfwd_w  <<<dim3(BB * CI * HH / 8), dim3(256), 0, stream>>>(x, Xc);
    kfwd_h  <<<dim3(BB * CI), dim3(256), 0, stream>>>(Xc, F);
    kmodes  <<<dim3(NJ * KX), dim3(256), 0, stream>>>(F, WC, mod1, mod2, OM);
    kinv_h  <<<dim3(BB * CO), dim3(256), 0, stream>>>(OM, G);
    kinv_w  <<<dim3(BB * CO * HH / 8), dim3(256), 0, stream>>>(G, y);
}

// Round 2
// 261.868 us; speedup vs baseline: 1.4742x; 1.4742x over previous
//
#include <hip/hip_runtime.h>

#define BB 8
#define CI 32
#define CO 32
#define HH 256
#define WW 256
#define HF 64
#define KX 32   // kept kx modes
#define NJ 64   // kept ky modes (0..31, 224..255)

typedef __attribute__((ext_vector_type(8))) short short8;
typedef __attribute__((ext_vector_type(4))) float f32x4;

__device__ __constant__ float PI2 = 6.28318530717958647692f;

// ---- fp32 -> bf16 split (hi + lo captures ~16 mantissa bits) ----
__device__ inline unsigned short f2bf(float f) {
    unsigned u = __float_as_uint(f);
    u += 0x7FFF + ((u >> 16) & 1);          // RNE
    return (unsigned short)(u >> 16);
}
__device__ inline void splitbf(float f, unsigned short& h, unsigned short& l) {
    unsigned short hh = f2bf(f);
    float fh = __uint_as_float(((unsigned)hh) << 16);
    l = f2bf(f - fh);
    h = hh;
}

// ---------------------------------------------------------------------------
// kprep: build MFMA-B-fragment-packed DFT matrices (bf16 hi/lo) in ws.
//  E (stage1, K=256,N=64): E[k=w][n=2kx+c] = c?-sin:cos (2*pi*w*kx/256)
//  D (stage5, K=64,N=256): D[k=2kx+c][n=w] = ck*(c?-sin:cos)(2*pi*kx*w/256), ck=kx?2:1
// B-frag mapping: n = lane&15, k = ktile*32 + (lane>>4)*8 + j  (j<8 contiguous)
// pk layout (ushort): [Ehi 16384][Elo 16384][Dhi 16384][Dlo 16384]
// ---------------------------------------------------------------------------
__global__ void kprep(unsigned short* __restrict__ pk) {
    int id = blockIdx.x * 256 + threadIdx.x;    // 0..32767
    if (id < 16384) {
        int j = id & 7, lane = (id >> 3) & 63, nt = (id >> 9) & 3, kt = id >> 11;
        int k = kt * 32 + (lane >> 4) * 8 + j;          // w
        int n = nt * 16 + (lane & 15);                  // 2kx+c
        int kx = n >> 1, c = n & 1;
        int p = (k * kx) & 255;
        float sn, cs; sincosf(PI2 * (float)p / 256.0f, &sn, &cs);
        float val = c ? -sn : cs;
        unsigned short h, l; splitbf(val, h, l);
        pk[id] = h; pk[id + 16384] = l;
    } else {
        int id2 = id - 16384;
        int j = id2 & 7, lane = (id2 >> 3) & 63, nt = (id2 >> 9) & 15, kt = id2 >> 13;
        int k = kt * 32 + (lane >> 4) * 8 + j;          // 2kx+c  (<64)
        int w = nt * 16 + (lane & 15);
        int kx = k >> 1, c = k & 1;
        int p = (kx * w) & 255;
        float sn, cs; sincosf(PI2 * (float)p / 256.0f, &sn, &cs);
        float ck = (kx == 0) ? 1.0f : 2.0f;
        float val = c ? -ck * sn : ck * cs;
        unsigned short h, l; splitbf(val, h, l);
        pk[id2 + 32768] = h; pk[id2 + 49152] = l;
    }
}

// ---------------------------------------------------------------------------
// Stage W: spectral weights (unchanged)
// ---------------------------------------------------------------------------
__global__ void kweights(const float* __restrict__ wts, const float* __restrict__ mlp,
                         float* __restrict__ WC) {
    int mode = blockIdx.x;            // s*1024 + m1*32 + m2
    int m1m2 = mode & 1023;
    int s = mode >> 10;
    __shared__ float rowr[HF];
    __shared__ float rowi[HF];
    int t = threadIdx.x;
    if (t < HF)           rowr[t]      = mlp[(m1m2 * 2 + 0) * HF + t];
    else if (t < 2 * HF)  rowi[t - HF] = mlp[(m1m2 * 2 + 1) * HF + (t - HF)];
    __syncthreads();
    int o = t & 31, i0 = t >> 5;
    #pragma unroll
    for (int ii = 0; ii < 4; ii++) {
        int i = i0 * 4 + ii;
        const float* wp = wts + ((i * CO + o) * 2 + s) * HF;
        float ar = 0.f, ai = 0.f;
        #pragma unroll 8
        for (int k = 0; k < HF; k++) {
            float wv = wp[k];
            ar = fmaf(wv, rowr[k], ar);
            ai = fmaf(wv, rowi[k], ai);
        }
        ((float2*)WC)[(mode * CI + i) * CO + o] = make_float2(ar, ai);
    }
}

// ---------------------------------------------------------------------------
// Stage 1 (MFMA): Xc[row][64] = X[row][256] * E[256][64], row=(b*CI+i)*H+h
// block: 128 rows x 64 cols, 4 waves (each wave 2 mtiles x 4 ntiles), K=256
// ---------------------------------------------------------------------------
__global__ __launch_bounds__(256) void kgemm1(const float* __restrict__ x,
                                              const unsigned short* __restrict__ pk,
                                              float* __restrict__ Xc) {
    __shared__ short B2[2][16384];      // 64 KB: Ehi, Elo frag-packed
    int t = threadIdx.x;
    {
        const uint4* src = (const uint4*)pk;        // 4096 uint4
        uint4* dst = (uint4*)&B2[0][0];
        #pragma unroll
        for (int q = 0; q < 16; q++) dst[t + q * 256] = src[t + q * 256];
    }
    __syncthreads();
    int wid = t >> 6, lane = t & 63;
    int row0 = blockIdx.x * 128 + wid * 32;
    int mrow = lane & 15, kq = lane >> 4;

    f32x4 acc[2][4];
    #pragma unroll
    for (int mi = 0; mi < 2; mi++)
        #pragma unroll
        for (int nt = 0; nt < 4; nt++)
            acc[mi][nt] = (f32x4){0.f, 0.f, 0.f, 0.f};

    #pragma unroll
    for (int kt = 0; kt < 8; kt++) {
        short8 ah[2], al[2];
        #pragma unroll
        for (int mi = 0; mi < 2; mi++) {
            const float4* ap = (const float4*)(x + (size_t)(row0 + mi * 16 + mrow) * 256 + kt * 32 + kq * 8);
            float4 v0 = ap[0], v1 = ap[1];
            float vals[8] = {v0.x, v0.y, v0.z, v0.w, v1.x, v1.y, v1.z, v1.w};
            #pragma unroll
            for (int e = 0; e < 8; e++) {
                unsigned short h, l; splitbf(vals[e], h, l);
                ah[mi][e] = (short)h; al[mi][e] = (short)l;
            }
        }
        #pragma unroll
        for (int nt = 0; nt < 4; nt++) {
            short8 bh = *(const short8*)&B2[0][((kt * 4 + nt) * 64 + lane) * 8];
            short8 bl = *(const short8*)&B2[1][((kt * 4 + nt) * 64 + lane) * 8];
            #pragma unroll
            for (int mi = 0; mi < 2; mi++) {
                acc[mi][nt] = __builtin_amdgcn_mfma_f32_16x16x32_bf16(ah[mi], bh, acc[mi][nt], 0, 0, 0);
                acc[mi][nt] = __builtin_amdgcn_mfma_f32_16x16x32_bf16(ah[mi], bl, acc[mi][nt], 0, 0, 0);
                acc[mi][nt] = __builtin_amdgcn_mfma_f32_16x16x32_bf16(al[mi], bh, acc[mi][nt], 0, 0, 0);
            }
        }
    }
    // C/D layout: col = lane&15, row = (lane>>4)*4 + reg  [m89]
    #pragma unroll
    for (int mi = 0; mi < 2; mi++)
        #pragma unroll
        for (int nt = 0; nt < 4; nt++)
            #pragma unroll
            for (int r = 0; r < 4; r++) {
                int grow = row0 + mi * 16 + kq * 4 + r;
                int gcol = nt * 16 + mrow;
                Xc[(size_t)grow * 64 + gcol] = acc[mi][nt][r];
            }
}

// ---------------------------------------------------------------------------
// Stage 2: forward DFT over h (fp32 recurrence), kx split over 4 blocks/slab
// grid (bi*4 + kq): LDS = Xc[bi][256][kq*8..+8] (16 KB); threads (j:64, g:4)
// ---------------------------------------------------------------------------
__global__ void kfwd_h(const float* __restrict__ Xc, float* __restrict__ F) {
    __shared__ float2 xs[HH][8];    // 16 KB
    int t = threadIdx.x;
    int bi = blockIdx.x >> 2, kq = blockIdx.x & 3;
    {
        const float4* src = (const float4*)Xc + (size_t)bi * (HH * 16);
        float4* dst = (float4*)&xs[0][0];       // 1024 float4
        #pragma unroll
        for (int q = 0; q < 4; q++) {
            int i4 = t + q * 256;
            int h = i4 >> 2, c4 = i4 & 3;
            dst[i4] = src[h * 16 + kq * 4 + c4];
        }
    }
    __syncthreads();
    int j = t & 63, g = t >> 6;                 // each thread: 2 kx
    int ky = (j < 32) ? j : (192 + j);
    float sn, cs;
    sincosf(-PI2 * (float)ky / 256.0f, &sn, &cs);
    float tr = 1.f, ti = 0.f;
    float a0r = 0.f, a0i = 0.f, a1r = 0.f, a1i = 0.f;
    #pragma unroll 4
    for (int h = 0; h < HH; h++) {
        float2 v0 = xs[h][g * 2 + 0];
        float2 v1 = xs[h][g * 2 + 1];
        a0r = fmaf(v0.x, tr, a0r); a0r = fmaf(-v0.y, ti, a0r);
        a0i = fmaf(v0.x, ti, a0i); a0i = fmaf(v0.y, tr, a0i);
        a1r = fmaf(v1.x, tr, a1r); a1r = fmaf(-v1.y, ti, a1r);
        a1i = fmaf(v1.x, ti, a1i); a1i = fmaf(v1.y, tr, a1i);
        float ntr = tr * cs - ti * sn;
        ti = fmaf(tr, sn, ti * cs);
        tr = ntr;
    }
    float2* Fo = ((float2*)F) + ((size_t)bi * NJ + j) * KX + kq * 8 + g * 2;
    Fo[0] = make_float2(a0r, a0i);
    Fo[1] = make_float2(a1r, a1i);
}

// ---------------------------------------------------------------------------
// Stage 3: mode mixing (unchanged)
// ---------------------------------------------------------------------------
__global__ void kmodes(const float* __restrict__ F, const float* __restrict__ WC,
                       const float* __restrict__ mod1, const float* __restrict__ mod2,
                       float* __restrict__ OM) {
    int m = blockIdx.x;             // j*32 + kx
    int j = m >> 5, kx = m & 31;
    int s = j >> 5;
    int m1 = j & 31, m2 = kx;
    __shared__ float2 fs[BB][CI];
    __shared__ float2 wcs[CI][CO];
    int t = threadIdx.x;
    {
        int b = t >> 5, i = t & 31;
        fs[b][i] = ((const float2*)F)[((size_t)(b * CI + i) * NJ + j) * KX + kx];
    }
    {
        const float2* wg = ((const float2*)WC) + (size_t)(s * 1024 + m1 * 32 + m2) * CI * CO;
        #pragma unroll
        for (int idx = t; idx < CI * CO; idx += 256) ((float2*)wcs)[idx] = wg[idx];
    }
    __syncthreads();
    int b = t >> 5, o = t & 31;
    float ar = 0.f, ai = 0.f;
    #pragma unroll 8
    for (int i = 0; i < CI; i++) {
        float2 f = fs[b][i];
        float2 w = wcs[i][o];
        ar = fmaf(f.x, w.x, ar);
        ar = fmaf(-f.y, w.y, ar);
        ai = fmaf(f.x, w.y, ai);
        ai = fmaf(f.y, w.x, ai);
    }
    const float* mp = (s == 0) ? mod1 : mod2;
    float mr = mp[(b * 1024 + m1 * 32 + m2) * 2 + 0];
    float mi = mp[(b * 1024 + m1 * 32 + m2) * 2 + 1];
    const float scale = 1.0f / 65536.0f;
    float outr = (ar * mr - ai * mi) * scale;
    float outi = (ar * mi + ai * mr) * scale;
    ((float2*)OM)[((size_t)(b * CO + o) * NJ + j) * KX + kx] = make_float2(outr, outi);
}

// ---------------------------------------------------------------------------
// Stage 4: inverse DFT over h (fp32 recurrence), kx split over 4 blocks
// grid (bo*4 + kq): LDS = OM[bo][64][kq*8..+8] (4 KB); thread = h, 8 kx accs
// ---------------------------------------------------------------------------
__global__ void kinv_h(const float* __restrict__ OM, float* __restrict__ G) {
    __shared__ float2 os[NJ][8];    // 4 KB
    int t = threadIdx.x;
    int bo = blockIdx.x >> 2, kq = blockIdx.x & 3;
    {
        const float4* src = (const float4*)OM + (size_t)bo * (NJ * 16);
        float4* dst = (float4*)&os[0][0];       // 256 float4
        int jj = t >> 2, c4 = t & 3;
        dst[t] = src[jj * 16 + kq * 4 + c4];
    }
    __syncthreads();
    int h = t;
    float sn, cs;
    sincosf(PI2 * (float)h / 256.0f, &sn, &cs);
    float tr = 1.f, ti = 0.f;
    float accr[8], acci[8];
    #pragma unroll
    for (int q = 0; q < 8; q++) { accr[q] = 0.f; acci[q] = 0.f; }
    for (int jj = 0; jj < NJ; jj++) {
        if (jj == 32) ti = -ti;     // e^{2pi i 32h/256} -> conj = e^{2pi i 224h/256}
        #pragma unroll
        for (int q = 0; q < 8; q++) {
            float2 v = os[jj][q];
            accr[q] = fmaf(v.x, tr, accr[q]);
            accr[q] = fmaf(-v.y, ti, accr[q]);
            acci[q] = fmaf(v.x, ti, acci[q]);
            acci[q] = fmaf(v.y, tr, acci[q]);
        }
        float ntr = tr * cs - ti * sn;
        ti = fmaf(tr, sn, ti * cs);
        tr = ntr;
    }
    float2* Go = ((float2*)G) + ((size_t)bo * HH + h) * KX + kq * 8;
    #pragma unroll
    for (int q = 0; q < 8; q++) Go[q] = make_float2(accr[q], acci[q]);
}

// ---------------------------------------------------------------------------
// Stage 5 (MFMA): y[row][256] = G[row][64] * D[64][256], row=(b*CO+o)*H+h
// block: 64 rows, 4 waves (each wave 1 mtile x 16 ntiles), K=64
// ---------------------------------------------------------------------------
__global__ __launch_bounds__(256) void kgemm5(const float* __restrict__ G,
                                              const unsigned short* __restrict__ pk,
                                              float* __restrict__ y) {
    __shared__ short B2[2][16384];      // 64 KB: Dhi, Dlo frag-packed
    int t = threadIdx.x;
    {
        const uint4* src = (const uint4*)(pk + 32768);
        uint4* dst = (uint4*)&B2[0][0];
        #pragma unroll
        for (int q = 0; q < 16; q++) dst[t + q * 256] = src[t + q * 256];
    }
    __syncthreads();
    int wid = t >> 6, lane = t & 63;
    int row0 = blockIdx.x * 64 + wid * 16;
    int mrow = lane & 15, kq = lane >> 4;

    f32x4 acc[16];
    #pragma unroll
    for (int nt = 0; nt < 16; nt++) acc[nt] = (f32x4){0.f, 0.f, 0.f, 0.f};

    #pragma unroll
    for (int kt = 0; kt < 2; kt++) {
        const float4* ap = (const float4*)(G + (size_t)(row0 + mrow) * 64 + kt * 32 + kq * 8);
        float4 v0 = ap[0], v1 = ap[1];
        float vals[8] = {v0.x, v0.y, v0.z, v0.w, v1.x, v1.y, v1.z, v1.w};
        short8 ah, al;
        #pragma unroll
        for (int e = 0; e < 8; e++) {
            unsigned short h, l; splitbf(vals[e], h, l);
            ah[e] = (short)h; al[e] = (short)l;
        }
        #pragma unroll
        for (int nt = 0; nt < 16; nt++) {
            short8 bh = *(const short8*)&B2[0][((kt * 16 + nt) * 64 + lane) * 8];
            short8 bl = *(const short8*)&B2[1][((kt * 16 + nt) * 64 + lane) * 8];
            acc[nt] = __builtin_amdgcn_mfma_f32_16x16x32_bf16(ah, bh, acc[nt], 0, 0, 0);
            acc[nt] = __builtin_amdgcn_mfma_f32_16x16x32_bf16(ah, bl, acc[nt], 0, 0, 0);
            acc[nt] = __builtin_amdgcn_mfma_f32_16x16x32_bf16(al, bh, acc[nt], 0, 0, 0);
        }
    }
    #pragma unroll
    for (int nt = 0; nt < 16; nt++)
        #pragma unroll
        for (int r = 0; r < 4; r++)
            y[(size_t)(row0 + kq * 4 + r) * 256 + nt * 16 + mrow] = acc[nt][r];
}

// ---------------------------------------------------------------------------
extern "C" void kernel_launch(void* const* d_in, const int* in_sizes, int n_in,
                              void* d_out, int out_size, void* d_ws, size_t ws_size,
                              hipStream_t stream) {
    const float* x    = (const float*)d_in[0];
    const float* mod1 = (const float*)d_in[1];
    const float* mod2 = (const float*)d_in[2];
    const float* wts  = (const float*)d_in[3];
    const float* mlp  = (const float*)d_in[4];
    float* y = (float*)d_out;

    float* ws = (float*)d_ws;
    float* Xc = ws;                         // 8*32*256*32*2  = 4,194,304 floats
    float* F  = Xc + 4194304;               // 1,048,576
    float* WC = F  + 1048576;               // 4,194,304
    float* OM = WC + 4194304;               // 1,048,576
    float* G  = OM + 1048576;               // 4,194,304
    unsigned short* pk = (unsigned short*)(G + 4194304);   // 65536 ushorts (128 KB)

    kprep   <<<dim3(128),  dim3(256), 0, stream>>>(pk);
    kweights<<<dim3(2048), dim3(256), 0, stream>>>(wts, mlp, WC);
    kgemm1  <<<dim3(512),  dim3(256), 0, stream>>>(x, pk, Xc);
    kfwd_h  <<<dim3(BB * CI * 4), dim3(256), 0, stream>>>(Xc, F);
    kmodes  <<<dim3(NJ * KX), dim3(256), 0, stream>>>(F, WC, mod1, mod2, OM);
    kinv_h  <<<dim3(BB * CO * 4), dim3(256), 0, stream>>>(OM, G);
    kgemm5  <<<dim3(1024), dim3(256), 0, stream>>>(G, pk, y);
}

// Round 3
// 207.571 us; speedup vs baseline: 1.8598x; 1.2616x over previous
//
#include <hip/hip_runtime.h>

#define BB 8
#define CI 32
#define CO 32
#define HH 256
#define WW 256
#define HF 64
#define KX 32   // kept kx modes
#define NJ 64   // kept ky modes (0..31, 224..255)

typedef __attribute__((ext_vector_type(8))) short short8;
typedef __attribute__((ext_vector_type(4))) float f32x4;

__device__ __constant__ float PI2 = 6.28318530717958647692f;

// ---- fp32 -> bf16 split (hi + lo captures ~16 mantissa bits) ----
__device__ inline unsigned short f2bf(float f) {
    unsigned u = __float_as_uint(f);
    u += 0x7FFF + ((u >> 16) & 1);          // RNE
    return (unsigned short)(u >> 16);
}
__device__ inline void splitbf(float f, unsigned short& h, unsigned short& l) {
    unsigned short hh = f2bf(f);
    float fh = __uint_as_float(((unsigned)hh) << 16);
    l = f2bf(f - fh);
    h = hh;
}

// ---------------------------------------------------------------------------
// kprep: build MFMA-B-fragment-packed DFT matrices (bf16 hi/lo) in ws.
//  E (stage1, K=256,N=64): E[k=w][n=2kx+c] = c?-sin:cos (2*pi*w*kx/256)
//  D (stage5, K=64,N=256): D[k=2kx+c][n=w] = ck*(c?-sin:cos)(2*pi*kx*w/256), ck=kx?2:1
// B-frag mapping: n = lane&15, k = ktile*32 + (lane>>4)*8 + j  (j<8 contiguous)
// pk layout (ushort): [Ehi 16384][Elo 16384][Dhi 16384][Dlo 16384]
// ---------------------------------------------------------------------------
__global__ void kprep(unsigned short* __restrict__ pk) {
    int id = blockIdx.x * 256 + threadIdx.x;    // 0..32767
    if (id < 16384) {
        int j = id & 7, lane = (id >> 3) & 63, nt = (id >> 9) & 3, kt = id >> 11;
        int k = kt * 32 + (lane >> 4) * 8 + j;          // w
        int n = nt * 16 + (lane & 15);                  // 2kx+c
        int kx = n >> 1, c = n & 1;
        int p = (k * kx) & 255;
        float sn, cs; sincosf(PI2 * (float)p / 256.0f, &sn, &cs);
        float val = c ? -sn : cs;
        unsigned short h, l; splitbf(val, h, l);
        pk[id] = h; pk[id + 16384] = l;
    } else {
        int id2 = id - 16384;
        int j = id2 & 7, lane = (id2 >> 3) & 63, nt = (id2 >> 9) & 15, kt = id2 >> 13;
        int k = kt * 32 + (lane >> 4) * 8 + j;          // 2kx+c  (<64)
        int w = nt * 16 + (lane & 15);
        int kx = k >> 1, c = k & 1;
        int p = (kx * w) & 255;
        float sn, cs; sincosf(PI2 * (float)p / 256.0f, &sn, &cs);
        float ck = (kx == 0) ? 1.0f : 2.0f;
        float val = c ? -ck * sn : ck * cs;
        unsigned short h, l; splitbf(val, h, l);
        pk[id2 + 32768] = h; pk[id2 + 49152] = l;
    }
}

// ---------------------------------------------------------------------------
// Stage W (MFMA): C[m][n] = dot(mlp_row(m), weights_row(n)) over K=64
//   m = c*1024 + m1m2   -> mlp row (m1m2*2 + c)
//   n = s*1024 + io     -> weights row (io*2 + s)
// WC layout: [s][m1m2][c][io] : addr = ((s*1024+m1m2)*2 + c)*1024 + io
// block: 128m x 128n, 4 waves (2x2), wave = 64x64 (4mt x 4nt), grid 16x16
// ---------------------------------------------------------------------------
__global__ __launch_bounds__(256) void kweights(const float* __restrict__ wts,
                                                const float* __restrict__ mlp,
                                                float* __restrict__ WC) {
    int t = threadIdx.x;
    int wid = t >> 6, lane = t & 63;
    int bm = blockIdx.x >> 4, bn = blockIdx.x & 15;
    int m0 = bm * 128 + (wid >> 1) * 64;
    int n0 = bn * 128 + (wid & 1) * 64;
    int l15 = lane & 15, lq = lane >> 4;

    f32x4 acc[4][4];
    #pragma unroll
    for (int mt = 0; mt < 4; mt++)
        #pragma unroll
        for (int nt = 0; nt < 4; nt++)
            acc[mt][nt] = (f32x4){0.f, 0.f, 0.f, 0.f};

    #pragma unroll
    for (int kt = 0; kt < 2; kt++) {
        short8 Ah[4], Al[4];
        #pragma unroll
        for (int mt = 0; mt < 4; mt++) {
            int m = m0 + mt * 16 + l15;
            int c = m >> 10, mm = m & 1023;
            const float4* p = (const float4*)(mlp + (mm * 2 + c) * 64 + kt * 32 + lq * 8);
            float4 v0 = p[0], v1 = p[1];
            float vals[8] = {v0.x, v0.y, v0.z, v0.w, v1.x, v1.y, v1.z, v1.w};
            #pragma unroll
            for (int e = 0; e < 8; e++) {
                unsigned short h, l; splitbf(vals[e], h, l);
                Ah[mt][e] = (short)h; Al[mt][e] = (short)l;
            }
        }
        #pragma unroll
        for (int nt = 0; nt < 4; nt++) {
            int n = n0 + nt * 16 + l15;
            int s = n >> 10, io = n & 1023;
            const float4* p = (const float4*)(wts + (io * 2 + s) * 64 + kt * 32 + lq * 8);
            float4 v0 = p[0], v1 = p[1];
            float vals[8] = {v0.x, v0.y, v0.z, v0.w, v1.x, v1.y, v1.z, v1.w};
            short8 Bh, Bl;
            #pragma unroll
            for (int e = 0; e < 8; e++) {
                unsigned short h, l; splitbf(vals[e], h, l);
                Bh[e] = (short)h; Bl[e] = (short)l;
            }
            #pragma unroll
            for (int mt = 0; mt < 4; mt++) {
                acc[mt][nt] = __builtin_amdgcn_mfma_f32_16x16x32_bf16(Ah[mt], Bh, acc[mt][nt], 0, 0, 0);
                acc[mt][nt] = __builtin_amdgcn_mfma_f32_16x16x32_bf16(Ah[mt], Bl, acc[mt][nt], 0, 0, 0);
                acc[mt][nt] = __builtin_amdgcn_mfma_f32_16x16x32_bf16(Al[mt], Bh, acc[mt][nt], 0, 0, 0);
            }
        }
    }
    // C/D: col(n) = lane&15, row(m) = (lane>>4)*4 + reg
    #pragma unroll
    for (int mt = 0; mt < 4; mt++)
        #pragma unroll
        for (int nt = 0; nt < 4; nt++)
            #pragma unroll
            for (int r = 0; r < 4; r++) {
                int m = m0 + mt * 16 + lq * 4 + r;
                int n = n0 + nt * 16 + l15;
                int addr = (((n >> 10) * 1024 + (m & 1023)) * 2 + (m >> 10)) * 1024 + (n & 1023);
                WC[addr] = acc[mt][nt][r];
            }
}

// ---------------------------------------------------------------------------
// Stage 1 (MFMA): Xc[row][64] = X[row][256] * E[256][64], row=(b*CI+i)*H+h
// block: 128 rows x 64 cols, 4 waves (each wave 2 mtiles x 4 ntiles), K=256
// ---------------------------------------------------------------------------
__global__ __launch_bounds__(256) void kgemm1(const float* __restrict__ x,
                                              const unsigned short* __restrict__ pk,
                                              float* __restrict__ Xc) {
    __shared__ short B2[2][16384];      // 64 KB: Ehi, Elo frag-packed
    int t = threadIdx.x;
    {
        const uint4* src = (const uint4*)pk;        // 4096 uint4
        uint4* dst = (uint4*)&B2[0][0];
        #pragma unroll
        for (int q = 0; q < 16; q++) dst[t + q * 256] = src[t + q * 256];
    }
    __syncthreads();
    int wid = t >> 6, lane = t & 63;
    int row0 = blockIdx.x * 128 + wid * 32;
    int mrow = lane & 15, kq = lane >> 4;

    f32x4 acc[2][4];
    #pragma unroll
    for (int mi = 0; mi < 2; mi++)
        #pragma unroll
        for (int nt = 0; nt < 4; nt++)
            acc[mi][nt] = (f32x4){0.f, 0.f, 0.f, 0.f};

    #pragma unroll
    for (int kt = 0; kt < 8; kt++) {
        short8 ah[2], al[2];
        #pragma unroll
        for (int mi = 0; mi < 2; mi++) {
            const float4* ap = (const float4*)(x + (size_t)(row0 + mi * 16 + mrow) * 256 + kt * 32 + kq * 8);
            float4 v0 = ap[0], v1 = ap[1];
            float vals[8] = {v0.x, v0.y, v0.z, v0.w, v1.x, v1.y, v1.z, v1.w};
            #pragma unroll
            for (int e = 0; e < 8; e++) {
                unsigned short h, l; splitbf(vals[e], h, l);
                ah[mi][e] = (short)h; al[mi][e] = (short)l;
            }
        }
        #pragma unroll
        for (int nt = 0; nt < 4; nt++) {
            short8 bh = *(const short8*)&B2[0][((kt * 4 + nt) * 64 + lane) * 8];
            short8 bl = *(const short8*)&B2[1][((kt * 4 + nt) * 64 + lane) * 8];
            #pragma unroll
            for (int mi = 0; mi < 2; mi++) {
                acc[mi][nt] = __builtin_amdgcn_mfma_f32_16x16x32_bf16(ah[mi], bh, acc[mi][nt], 0, 0, 0);
                acc[mi][nt] = __builtin_amdgcn_mfma_f32_16x16x32_bf16(ah[mi], bl, acc[mi][nt], 0, 0, 0);
                acc[mi][nt] = __builtin_amdgcn_mfma_f32_16x16x32_bf16(al[mi], bh, acc[mi][nt], 0, 0, 0);
            }
        }
    }
    // C/D layout: col = lane&15, row = (lane>>4)*4 + reg  [m89]
    #pragma unroll
    for (int mi = 0; mi < 2; mi++)
        #pragma unroll
        for (int nt = 0; nt < 4; nt++)
            #pragma unroll
            for (int r = 0; r < 4; r++) {
                int grow = row0 + mi * 16 + kq * 4 + r;
                int gcol = nt * 16 + mrow;
                Xc[(size_t)grow * 64 + gcol] = acc[mi][nt][r];
            }
}

// ---------------------------------------------------------------------------
// Stage 2: forward DFT over h (fp32 recurrence), kx split over 4 blocks/slab
// grid (bi*4 + kq): LDS = Xc[bi][256][kq*8..+8] (16 KB); threads (j:64, g:4)
// ---------------------------------------------------------------------------
__global__ void kfwd_h(const float* __restrict__ Xc, float* __restrict__ F) {
    __shared__ float2 xs[HH][8];    // 16 KB
    int t = threadIdx.x;
    int bi = blockIdx.x >> 2, kq = blockIdx.x & 3;
    {
        const float4* src = (const float4*)Xc + (size_t)bi * (HH * 16);
        float4* dst = (float4*)&xs[0][0];       // 1024 float4
        #pragma unroll
        for (int q = 0; q < 4; q++) {
            int i4 = t + q * 256;
            int h = i4 >> 2, c4 = i4 & 3;
            dst[i4] = src[h * 16 + kq * 4 + c4];
        }
    }
    __syncthreads();
    int j = t & 63, g = t >> 6;                 // each thread: 2 kx
    int ky = (j < 32) ? j : (192 + j);
    float sn, cs;
    sincosf(-PI2 * (float)ky / 256.0f, &sn, &cs);
    float tr = 1.f, ti = 0.f;
    float a0r = 0.f, a0i = 0.f, a1r = 0.f, a1i = 0.f;
    #pragma unroll 4
    for (int h = 0; h < HH; h++) {
        float2 v0 = xs[h][g * 2 + 0];
        float2 v1 = xs[h][g * 2 + 1];
        a0r = fmaf(v0.x, tr, a0r); a0r = fmaf(-v0.y, ti, a0r);
        a0i = fmaf(v0.x, ti, a0i); a0i = fmaf(v0.y, tr, a0i);
        a1r = fmaf(v1.x, tr, a1r); a1r = fmaf(-v1.y, ti, a1r);
        a1i = fmaf(v1.x, ti, a1i); a1i = fmaf(v1.y, tr, a1i);
        float ntr = tr * cs - ti * sn;
        ti = fmaf(tr, sn, ti * cs);
        tr = ntr;
    }
    float2* Fo = ((float2*)F) + ((size_t)bi * NJ + j) * KX + kq * 8 + g * 2;
    Fo[0] = make_float2(a0r, a0i);
    Fo[1] = make_float2(a1r, a1i);
}

// ---------------------------------------------------------------------------
// Stage 3: mode mixing. WC layout now [s][m1m2][c][io].
// ---------------------------------------------------------------------------
__global__ void kmodes(const float* __restrict__ F, const float* __restrict__ WC,
                       const float* __restrict__ mod1, const float* __restrict__ mod2,
                       float* __restrict__ OM) {
    int m = blockIdx.x;             // j*32 + kx
    int j = m >> 5, kx = m & 31;
    int s = j >> 5;
    int m1 = j & 31, m2 = kx;
    __shared__ float2 fs[BB][CI];
    __shared__ float wcr[CI * CO];
    __shared__ float wci[CI * CO];
    int t = threadIdx.x;
    {
        int b = t >> 5, i = t & 31;
        fs[b][i] = ((const float2*)F)[((size_t)(b * CI + i) * NJ + j) * KX + kx];
    }
    {
        const float4* wg = (const float4*)(WC + ((size_t)(s * 1024 + m1 * 32 + m2) * 2) * 1024);
        ((float4*)wcr)[t] = wg[t];
        ((float4*)wci)[t] = wg[t + 256];
    }
    __syncthreads();
    int b = t >> 5, o = t & 31;
    float ar = 0.f, ai = 0.f;
    #pragma unroll 8
    for (int i = 0; i < CI; i++) {
        float2 f = fs[b][i];
        float wx = wcr[i * 32 + o];
        float wy = wci[i * 32 + o];
        ar = fmaf(f.x, wx, ar);
        ar = fmaf(-f.y, wy, ar);
        ai = fmaf(f.x, wy, ai);
        ai = fmaf(f.y, wx, ai);
    }
    const float* mp = (s == 0) ? mod1 : mod2;
    float mr = mp[(b * 1024 + m1 * 32 + m2) * 2 + 0];
    float mi = mp[(b * 1024 + m1 * 32 + m2) * 2 + 1];
    const float scale = 1.0f / 65536.0f;
    float outr = (ar * mr - ai * mi) * scale;
    float outi = (ar * mi + ai * mr) * scale;
    ((float2*)OM)[((size_t)(b * CO + o) * NJ + j) * KX + kx] = make_float2(outr, outi);
}

// ---------------------------------------------------------------------------
// Stage 4: inverse DFT over h (fp32 recurrence), kx split over 4 blocks
// ---------------------------------------------------------------------------
__global__ void kinv_h(const float* __restrict__ OM, float* __restrict__ G) {
    __shared__ float2 os[NJ][8];    // 4 KB
    int t = threadIdx.x;
    int bo = blockIdx.x >> 2, kq = blockIdx.x & 3;
    {
        const float4* src = (const float4*)OM + (size_t)bo * (NJ * 16);
        float4* dst = (float4*)&os[0][0];       // 256 float4
        int jj = t >> 2, c4 = t & 3;
        dst[t] = src[jj * 16 + kq * 4 + c4];
    }
    __syncthreads();
    int h = t;
    float sn, cs;
    sincosf(PI2 * (float)h / 256.0f, &sn, &cs);
    float tr = 1.f, ti = 0.f;
    float accr[8], acci[8];
    #pragma unroll
    for (int q = 0; q < 8; q++) { accr[q] = 0.f; acci[q] = 0.f; }
    for (int jj = 0; jj < NJ; jj++) {
        if (jj == 32) ti = -ti;     // e^{2pi i 32h/256} -> conj = e^{2pi i 224h/256}
        #pragma unroll
        for (int q = 0; q < 8; q++) {
            float2 v = os[jj][q];
            accr[q] = fmaf(v.x, tr, accr[q]);
            accr[q] = fmaf(-v.y, ti, accr[q]);
            acci[q] = fmaf(v.x, ti, acci[q]);
            acci[q] = fmaf(v.y, tr, acci[q]);
        }
        float ntr = tr * cs - ti * sn;
        ti = fmaf(tr, sn, ti * cs);
        tr = ntr;
    }
    float2* Go = ((float2*)G) + ((size_t)bo * HH + h) * KX + kq * 8;
    #pragma unroll
    for (int q = 0; q < 8; q++) Go[q] = make_float2(accr[q], acci[q]);
}

// ---------------------------------------------------------------------------
// Stage 5 (MFMA): y[row][256] = G[row][64] * D[64][256], row=(b*CO+o)*H+h
// ---------------------------------------------------------------------------
__global__ __launch_bounds__(256) void kgemm5(const float* __restrict__ G,
                                              const unsigned short* __restrict__ pk,
                                              float* __restrict__ y) {
    __shared__ short B2[2][16384];      // 64 KB: Dhi, Dlo frag-packed
    int t = threadIdx.x;
    {
        const uint4* src = (const uint4*)(pk + 32768);
        uint4* dst = (uint4*)&B2[0][0];
        #pragma unroll
        for (int q = 0; q < 16; q++) dst[t + q * 256] = src[t + q * 256];
    }
    __syncthreads();
    int wid = t >> 6, lane = t & 63;
    int row0 = blockIdx.x * 64 + wid * 16;
    int mrow = lane & 15, kq = lane >> 4;

    f32x4 acc[16];
    #pragma unroll
    for (int nt = 0; nt < 16; nt++) acc[nt] = (f32x4){0.f, 0.f, 0.f, 0.f};

    #pragma unroll
    for (int kt = 0; kt < 2; kt++) {
        const float4* ap = (const float4*)(G + (size_t)(row0 + mrow) * 64 + kt * 32 + kq * 8);
        float4 v0 = ap[0], v1 = ap[1];
        float vals[8] = {v0.x, v0.y, v0.z, v0.w, v1.x, v1.y, v1.z, v1.w};
        short8 ah, al;
        #pragma unroll
        for (int e = 0; e < 8; e++) {
            unsigned short h, l; splitbf(vals[e], h, l);
            ah[e] = (short)h; al[e] = (short)l;
        }
        #pragma unroll
        for (int nt = 0; nt < 16; nt++) {
            short8 bh = *(const short8*)&B2[0][((kt * 16 + nt) * 64 + lane) * 8];
            short8 bl = *(const short8*)&B2[1][((kt * 16 + nt) * 64 + lane) * 8];
            acc[nt] = __builtin_amdgcn_mfma_f32_16x16x32_bf16(ah, bh, acc[nt], 0, 0, 0);
            acc[nt] = __builtin_amdgcn_mfma_f32_16x16x32_bf16(ah, bl, acc[nt], 0, 0, 0);
            acc[nt] = __builtin_amdgcn_mfma_f32_16x16x32_bf16(al, bh, acc[nt], 0, 0, 0);
        }
    }
    #pragma unroll
    for (int nt = 0; nt < 16; nt++)
        #pragma unroll
        for (int r = 0; r < 4; r++)
            y[(size_t)(row0 + kq * 4 + r) * 256 + nt * 16 + mrow] = acc[nt][r];
}

// ---------------------------------------------------------------------------
extern "C" void kernel_launch(void* const* d_in, const int* in_sizes, int n_in,
                              void* d_out, int out_size, void* d_ws, size_t ws_size,
                              hipStream_t stream) {
    const float* x    = (const float*)d_in[0];
    const float* mod1 = (const float*)d_in[1];
    const float* mod2 = (const float*)d_in[2];
    const float* wts  = (const float*)d_in[3];
    const float* mlp  = (const float*)d_in[4];
    float* y = (float*)d_out;

    float* ws = (float*)d_ws;
    float* Xc = ws;                         // 4,194,304 floats
    float* F  = Xc + 4194304;               // 1,048,576
    float* WC = F  + 1048576;               // 4,194,304
    float* OM = WC + 4194304;               // 1,048,576
    float* G  = OM + 1048576;               // 4,194,304
    unsigned short* pk = (unsigned short*)(G + 4194304);   // 65536 ushorts

    kprep   <<<dim3(128),  dim3(256), 0, stream>>>(pk);
    kweights<<<dim3(256),  dim3(256), 0, stream>>>(wts, mlp, WC);
    kgemm1  <<<dim3(512),  dim3(256), 0, stream>>>(x, pk, Xc);
    kfwd_h  <<<dim3(BB * CI * 4), dim3(256), 0, stream>>>(Xc, F);
    kmodes  <<<dim3(NJ * KX), dim3(256), 0, stream>>>(F, WC, mod1, mod2, OM);
    kinv_h  <<<dim3(BB * CO * 4), dim3(256), 0, stream>>>(OM, G);
    kgemm5  <<<dim3(1024), dim3(256), 0, stream>>>(G, pk, y);
}

// Round 4
// 198.486 us; speedup vs baseline: 1.9449x; 1.0458x over previous
//
#include <hip/hip_runtime.h>

#define BB 8
#define CI 32
#define CO 32
#define HH 256
#define WW 256
#define HF 64
#define KX 32   // kept kx modes
#define NJ 64   // kept ky modes (0..31, 224..255)

typedef __attribute__((ext_vector_type(8))) short short8;
typedef __attribute__((ext_vector_type(4))) float f32x4;

__device__ __constant__ float PI2 = 6.28318530717958647692f;

// ---- fp32 -> bf16 split (hi + lo captures ~16 mantissa bits) ----
__device__ inline unsigned short f2bf(float f) {
    unsigned u = __float_as_uint(f);
    u += 0x7FFF + ((u >> 16) & 1);          // RNE
    return (unsigned short)(u >> 16);
}
__device__ inline void splitbf(float f, unsigned short& h, unsigned short& l) {
    unsigned short hh = f2bf(f);
    float fh = __uint_as_float(((unsigned)hh) << 16);
    l = f2bf(f - fh);
    h = hh;
}

// ---------------------------------------------------------------------------
// kprep: build MFMA-B-fragment-packed DFT matrices (bf16 hi/lo) in ws.
//  E (stage1, K=256,N=64): E[k=w][n=2kx+c] = c?-sin:cos (2*pi*w*kx/256)
//  D (stage5, K=64,N=256): D[k=2kx+c][n=w] = ck*(c?-sin:cos)(2*pi*kx*w/256), ck=kx?2:1
// B-frag mapping: n = lane&15, k = ktile*32 + (lane>>4)*8 + j
// pk layout (ushort): [Ehi 16384][Elo 16384][Dhi 16384][Dlo 16384]
// ---------------------------------------------------------------------------
__global__ void kprep(unsigned short* __restrict__ pk) {
    int id = blockIdx.x * 256 + threadIdx.x;    // 0..32767
    if (id < 16384) {
        int j = id & 7, lane = (id >> 3) & 63, nt = (id >> 9) & 3, kt = id >> 11;
        int k = kt * 32 + (lane >> 4) * 8 + j;          // w
        int n = nt * 16 + (lane & 15);                  // 2kx+c
        int kx = n >> 1, c = n & 1;
        int p = (k * kx) & 255;
        float sn, cs; sincosf(PI2 * (float)p / 256.0f, &sn, &cs);
        float val = c ? -sn : cs;
        unsigned short h, l; splitbf(val, h, l);
        pk[id] = h; pk[id + 16384] = l;
    } else {
        int id2 = id - 16384;
        int j = id2 & 7, lane = (id2 >> 3) & 63, nt = (id2 >> 9) & 15, kt = id2 >> 13;
        int k = kt * 32 + (lane >> 4) * 8 + j;          // 2kx+c  (<64)
        int w = nt * 16 + (lane & 15);
        int kx = k >> 1, c = k & 1;
        int p = (kx * w) & 255;
        float sn, cs; sincosf(PI2 * (float)p / 256.0f, &sn, &cs);
        float ck = (kx == 0) ? 1.0f : 2.0f;
        float val = c ? -ck * sn : ck * cs;
        unsigned short h, l; splitbf(val, h, l);
        pk[id2 + 32768] = h; pk[id2 + 49152] = l;
    }
}

// ---------------------------------------------------------------------------
// Stage W (MFMA): WC[s][m1m2][c][io] = dot(mlp_row, weights_row) over K=64
// ---------------------------------------------------------------------------
__global__ __launch_bounds__(256) void kweights(const float* __restrict__ wts,
                                                const float* __restrict__ mlp,
                                                float* __restrict__ WC) {
    int t = threadIdx.x;
    int wid = t >> 6, lane = t & 63;
    int bm = blockIdx.x >> 4, bn = blockIdx.x & 15;
    int m0 = bm * 128 + (wid >> 1) * 64;
    int n0 = bn * 128 + (wid & 1) * 64;
    int l15 = lane & 15, lq = lane >> 4;

    f32x4 acc[4][4];
    #pragma unroll
    for (int mt = 0; mt < 4; mt++)
        #pragma unroll
        for (int nt = 0; nt < 4; nt++)
            acc[mt][nt] = (f32x4){0.f, 0.f, 0.f, 0.f};

    #pragma unroll
    for (int kt = 0; kt < 2; kt++) {
        short8 Ah[4], Al[4];
        #pragma unroll
        for (int mt = 0; mt < 4; mt++) {
            int m = m0 + mt * 16 + l15;
            int c = m >> 10, mm = m & 1023;
            const float4* p = (const float4*)(mlp + (mm * 2 + c) * 64 + kt * 32 + lq * 8);
            float4 v0 = p[0], v1 = p[1];
            float vals[8] = {v0.x, v0.y, v0.z, v0.w, v1.x, v1.y, v1.z, v1.w};
            #pragma unroll
            for (int e = 0; e < 8; e++) {
                unsigned short h, l; splitbf(vals[e], h, l);
                Ah[mt][e] = (short)h; Al[mt][e] = (short)l;
            }
        }
        #pragma unroll
        for (int nt = 0; nt < 4; nt++) {
            int n = n0 + nt * 16 + l15;
            int s = n >> 10, io = n & 1023;
            const float4* p = (const float4*)(wts + (io * 2 + s) * 64 + kt * 32 + lq * 8);
            float4 v0 = p[0], v1 = p[1];
            float vals[8] = {v0.x, v0.y, v0.z, v0.w, v1.x, v1.y, v1.z, v1.w};
            short8 Bh, Bl;
            #pragma unroll
            for (int e = 0; e < 8; e++) {
                unsigned short h, l; splitbf(vals[e], h, l);
                Bh[e] = (short)h; Bl[e] = (short)l;
            }
            #pragma unroll
            for (int mt = 0; mt < 4; mt++) {
                acc[mt][nt] = __builtin_amdgcn_mfma_f32_16x16x32_bf16(Ah[mt], Bh, acc[mt][nt], 0, 0, 0);
                acc[mt][nt] = __builtin_amdgcn_mfma_f32_16x16x32_bf16(Ah[mt], Bl, acc[mt][nt], 0, 0, 0);
                acc[mt][nt] = __builtin_amdgcn_mfma_f32_16x16x32_bf16(Al[mt], Bh, acc[mt][nt], 0, 0, 0);
            }
        }
    }
    #pragma unroll
    for (int mt = 0; mt < 4; mt++)
        #pragma unroll
        for (int nt = 0; nt < 4; nt++)
            #pragma unroll
            for (int r = 0; r < 4; r++) {
                int m = m0 + mt * 16 + lq * 4 + r;
                int n = n0 + nt * 16 + l15;
                int addr = (((n >> 10) * 1024 + (m & 1023)) * 2 + (m >> 10)) * 1024 + (n & 1023);
                WC[addr] = acc[mt][nt][r];
            }
}

// ---------------------------------------------------------------------------
// kfwd (fused stages 1+2): block = one (b,i) slab (256 rows of x), 512 thr.
//  Stage 1 (MFMA): Xc[h][kx] = X[h][:] * E, written to LDS [h][64] fp32.
//    E fragments streamed from L2 (pk). Wave w: rows [w*32, w*32+32).
//  Stage 2 (VALU): F[j][kx] = sum_h T[j][h]*Xc[h][kx], wave w: kx [w*4,w*4+4),
//    lane = j. LDS reads are wave-broadcast (conflict-free).
// ---------------------------------------------------------------------------
__global__ __launch_bounds__(512) void kfwd(const float* __restrict__ x,
                                            const unsigned short* __restrict__ pk,
                                            float* __restrict__ F) {
    __shared__ float xs[HH * 64];       // 64 KB
    int t = threadIdx.x;
    int bi = blockIdx.x;
    int w = t >> 6, lane = t & 63;
    int l15 = lane & 15, lq = lane >> 4;

    // ---- stage 1 ----
    f32x4 acc[2][4];
    #pragma unroll
    for (int mt = 0; mt < 2; mt++)
        #pragma unroll
        for (int nt = 0; nt < 4; nt++)
            acc[mt][nt] = (f32x4){0.f, 0.f, 0.f, 0.f};

    #pragma unroll
    for (int kt = 0; kt < 8; kt++) {
        short8 bh[4], bl[4];
        #pragma unroll
        for (int nt = 0; nt < 4; nt++) {
            bh[nt] = *(const short8*)(pk + ((size_t)((kt * 4 + nt) * 64 + lane)) * 8);
            bl[nt] = *(const short8*)(pk + 16384 + ((size_t)((kt * 4 + nt) * 64 + lane)) * 8);
        }
        #pragma unroll
        for (int mt = 0; mt < 2; mt++) {
            const float4* ap = (const float4*)(x + (size_t)(bi * 256 + w * 32 + mt * 16 + l15) * 256 + kt * 32 + lq * 8);
            float4 v0 = ap[0], v1 = ap[1];
            float vals[8] = {v0.x, v0.y, v0.z, v0.w, v1.x, v1.y, v1.z, v1.w};
            short8 ah, al;
            #pragma unroll
            for (int e = 0; e < 8; e++) {
                unsigned short h, l; splitbf(vals[e], h, l);
                ah[e] = (short)h; al[e] = (short)l;
            }
            #pragma unroll
            for (int nt = 0; nt < 4; nt++) {
                acc[mt][nt] = __builtin_amdgcn_mfma_f32_16x16x32_bf16(ah, bh[nt], acc[mt][nt], 0, 0, 0);
                acc[mt][nt] = __builtin_amdgcn_mfma_f32_16x16x32_bf16(ah, bl[nt], acc[mt][nt], 0, 0, 0);
                acc[mt][nt] = __builtin_amdgcn_mfma_f32_16x16x32_bf16(al, bh[nt], acc[mt][nt], 0, 0, 0);
            }
        }
    }
    // write to LDS: row = w*32 + mt*16 + lq*4 + r, col n = nt*16 + l15 (n = 2kx+c)
    #pragma unroll
    for (int mt = 0; mt < 2; mt++)
        #pragma unroll
        for (int nt = 0; nt < 4; nt++)
            #pragma unroll
            for (int r = 0; r < 4; r++)
                xs[(w * 32 + mt * 16 + lq * 4 + r) * 64 + nt * 16 + l15] = acc[mt][nt][r];
    __syncthreads();

    // ---- stage 2 ----  wave w: kx in [w*4, w*4+4); lane = j
    int j = lane;
    int ky = (j < 32) ? j : (192 + j);
    float sn, cs;
    sincosf(-PI2 * (float)ky / 256.0f, &sn, &cs);
    float tr = 1.f, ti = 0.f;
    float ar[4], ai[4];
    #pragma unroll
    for (int q = 0; q < 4; q++) { ar[q] = 0.f; ai[q] = 0.f; }
    #pragma unroll 4
    for (int h = 0; h < HH; h++) {
        #pragma unroll
        for (int q = 0; q < 4; q++) {
            float2 v = *(const float2*)&xs[h * 64 + (w * 4 + q) * 2];
            ar[q] = fmaf(v.x, tr, ar[q]); ar[q] = fmaf(-v.y, ti, ar[q]);
            ai[q] = fmaf(v.x, ti, ai[q]); ai[q] = fmaf(v.y, tr, ai[q]);
        }
        float ntr = tr * cs - ti * sn;
        ti = fmaf(tr, sn, ti * cs);
        tr = ntr;
    }
    float2* Fo = ((float2*)F) + ((size_t)bi * NJ + j) * KX + w * 4;
    #pragma unroll
    for (int q = 0; q < 4; q++) Fo[q] = make_float2(ar[q], ai[q]);
}

// ---------------------------------------------------------------------------
// Stage 3: mode mixing. WC layout [s][m1m2][c][io].
// ---------------------------------------------------------------------------
__global__ void kmodes(const float* __restrict__ F, const float* __restrict__ WC,
                       const float* __restrict__ mod1, const float* __restrict__ mod2,
                       float* __restrict__ OM) {
    int m = blockIdx.x;             // j*32 + kx
    int j = m >> 5, kx = m & 31;
    int s = j >> 5;
    int m1 = j & 31, m2 = kx;
    __shared__ float2 fs[BB][CI];
    __shared__ float wcr[CI * CO];
    __shared__ float wci[CI * CO];
    int t = threadIdx.x;
    {
        int b = t >> 5, i = t & 31;
        fs[b][i] = ((const float2*)F)[((size_t)(b * CI + i) * NJ + j) * KX + kx];
    }
    {
        const float4* wg = (const float4*)(WC + ((size_t)(s * 1024 + m1 * 32 + m2) * 2) * 1024);
        ((float4*)wcr)[t] = wg[t];
        ((float4*)wci)[t] = wg[t + 256];
    }
    __syncthreads();
    int b = t >> 5, o = t & 31;
    float ar = 0.f, ai = 0.f;
    #pragma unroll 8
    for (int i = 0; i < CI; i++) {
        float2 f = fs[b][i];
        float wx = wcr[i * 32 + o];
        float wy = wci[i * 32 + o];
        ar = fmaf(f.x, wx, ar);
        ar = fmaf(-f.y, wy, ar);
        ai = fmaf(f.x, wy, ai);
        ai = fmaf(f.y, wx, ai);
    }
    const float* mp = (s == 0) ? mod1 : mod2;
    float mr = mp[(b * 1024 + m1 * 32 + m2) * 2 + 0];
    float mi = mp[(b * 1024 + m1 * 32 + m2) * 2 + 1];
    const float scale = 1.0f / 65536.0f;
    float outr = (ar * mr - ai * mi) * scale;
    float outi = (ar * mi + ai * mr) * scale;
    ((float2*)OM)[((size_t)(b * CO + o) * NJ + j) * KX + kx] = make_float2(outr, outi);
}

// ---------------------------------------------------------------------------
// kinv (fused stages 4+5): block = one (b,o) slab, 512 thr. 64 KB LDS reused:
//  phase A: os = OM[bo] (first 16 KB). Stage 4 (VALU): thread (h=t&255,
//    half=t>>8) computes G[h][kx] for 16 kx; twiddle recurrence over j.
//  phase B (after barrier): G written into LDS in A-fragment-ready layout:
//    addr(k,h) = (k>>3)*2048 + h*8 + (k&7)   (k = 2kx+c)
//  Stage 5 (MFMA): y[h][:] = G[h][:] * D, D fragments streamed from L2.
// ---------------------------------------------------------------------------
__global__ __launch_bounds__(512) void kinv(const float* __restrict__ OM,
                                            const unsigned short* __restrict__ pk,
                                            float* __restrict__ y) {
    __shared__ float smem[16384];       // 64 KB
    float2* os = (float2*)smem;         // [64][32] float2, first 16 KB
    int t = threadIdx.x;
    int bo = blockIdx.x;
    {
        const float4* src = (const float4*)OM + (size_t)bo * 1024;
        ((float4*)smem)[t] = src[t];
        ((float4*)smem)[t + 512] = src[t + 512];
    }
    __syncthreads();

    // ---- stage 4 ----
    int h = t & 255, half = t >> 8;
    float sn, cs;
    sincosf(PI2 * (float)h / 256.0f, &sn, &cs);
    float tr = 1.f, ti = 0.f;
    float accr[16], acci[16];
    #pragma unroll
    for (int q = 0; q < 16; q++) { accr[q] = 0.f; acci[q] = 0.f; }
    for (int j = 0; j < NJ; j++) {
        if (j == 32) ti = -ti;
        #pragma unroll
        for (int q = 0; q < 16; q++) {
            float2 v = os[j * 32 + half * 16 + q];
            accr[q] = fmaf(v.x, tr, accr[q]);
            accr[q] = fmaf(-v.y, ti, accr[q]);
            acci[q] = fmaf(v.x, ti, acci[q]);
            acci[q] = fmaf(v.y, tr, acci[q]);
        }
        float ntr = tr * cs - ti * sn;
        ti = fmaf(tr, sn, ti * cs);
        tr = ntr;
    }
    __syncthreads();        // all os reads done; smem becomes gs
    #pragma unroll
    for (int q = 0; q < 16; q++) {
        int kx = half * 16 + q;
        // k0 = 2kx: addr = (kx>>2)*2048 + h*8 + ((2kx)&6), pair (re,im)
        *(float2*)&smem[(kx >> 2) * 2048 + h * 8 + ((2 * kx) & 6)] = make_float2(accr[q], acci[q]);
    }
    __syncthreads();

    // ---- stage 5 ----  wave w: cols [w*32, w*32+32) (nt = w*2+ntl)
    int w = t >> 6, lane = t & 63;
    int l15 = lane & 15, lq = lane >> 4;
    const unsigned short* pkD = pk + 32768;
    short8 Bh[2][2], Bl[2][2];
    #pragma unroll
    for (int kt = 0; kt < 2; kt++)
        #pragma unroll
        for (int ntl = 0; ntl < 2; ntl++) {
            int nt = w * 2 + ntl;
            Bh[kt][ntl] = *(const short8*)(pkD + ((size_t)((kt * 16 + nt) * 64 + lane)) * 8);
            Bl[kt][ntl] = *(const short8*)(pkD + 16384 + ((size_t)((kt * 16 + nt) * 64 + lane)) * 8);
        }
    #pragma unroll 4
    for (int mt = 0; mt < 16; mt++) {
        f32x4 acc2[2];
        acc2[0] = (f32x4){0.f, 0.f, 0.f, 0.f};
        acc2[1] = (f32x4){0.f, 0.f, 0.f, 0.f};
        #pragma unroll
        for (int kt = 0; kt < 2; kt++) {
            // A frag: h = mt*16+l15, k octet = kt*4+lq
            const float* ap = &smem[(kt * 4 + lq) * 2048 + (mt * 16 + l15) * 8];
            short8 ah, al;
            #pragma unroll
            for (int e = 0; e < 8; e++) {
                unsigned short hh, ll; splitbf(ap[e], hh, ll);
                ah[e] = (short)hh; al[e] = (short)ll;
            }
            #pragma unroll
            for (int ntl = 0; ntl < 2; ntl++) {
                acc2[ntl] = __builtin_amdgcn_mfma_f32_16x16x32_bf16(ah, Bh[kt][ntl], acc2[ntl], 0, 0, 0);
                acc2[ntl] = __builtin_amdgcn_mfma_f32_16x16x32_bf16(ah, Bl[kt][ntl], acc2[ntl], 0, 0, 0);
                acc2[ntl] = __builtin_amdgcn_mfma_f32_16x16x32_bf16(al, Bh[kt][ntl], acc2[ntl], 0, 0, 0);
            }
        }
        #pragma unroll
        for (int ntl = 0; ntl < 2; ntl++)
            #pragma unroll
            for (int r = 0; r < 4; r++)
                y[(size_t)(bo * 256 + mt * 16 + lq * 4 + r) * 256 + (w * 2 + ntl) * 16 + l15] = acc2[ntl][r];
    }
}

// ---------------------------------------------------------------------------
extern "C" void kernel_launch(void* const* d_in, const int* in_sizes, int n_in,
                              void* d_out, int out_size, void* d_ws, size_t ws_size,
                              hipStream_t stream) {
    const float* x    = (const float*)d_in[0];
    const float* mod1 = (const float*)d_in[1];
    const float* mod2 = (const float*)d_in[2];
    const float* wts  = (const float*)d_in[3];
    const float* mlp  = (const float*)d_in[4];
    float* y = (float*)d_out;

    float* ws = (float*)d_ws;
    float* F  = ws;                         // 1,048,576 floats
    float* WC = F + 1048576;                // 4,194,304
    float* OM = WC + 4194304;               // 1,048,576
    unsigned short* pk = (unsigned short*)(OM + 1048576);   // 65536 ushorts

    kprep   <<<dim3(128),  dim3(256), 0, stream>>>(pk);
    kweights<<<dim3(256),  dim3(256), 0, stream>>>(wts, mlp, WC);
    kfwd    <<<dim3(BB * CI), dim3(512), 0, stream>>>(x, pk, F);
    kmodes  <<<dim3(NJ * KX), dim3(256), 0, stream>>>(F, WC, mod1, mod2, OM);
    kinv    <<<dim3(BB * CO), dim3(512), 0, stream>>>(OM, pk, y);
}

// Round 5
// 166.547 us; speedup vs baseline: 2.3179x; 1.1918x over previous
//
#include <hip/hip_runtime.h>

#define BB 8
#define CI 32
#define CO 32
#define HH 256
#define WW 256
#define HF 64
#define KX 32   // kept kx modes
#define NJ 64   // kept ky modes (0..31, 224..255)

typedef __attribute__((ext_vector_type(8))) short short8;
typedef __attribute__((ext_vector_type(4))) float f32x4;

__device__ __constant__ float PI2 = 6.28318530717958647692f;

// pk layout (ushort offsets):
//  E  B-frags (stage1):  hi 0,      lo 16384
//  D  B-frags (stage5):  hi 32768,  lo 49152
//  Tf A-frags (fwd-h):   cos-hi 65536, cos-lo 81920, sin-hi 98304, sin-lo 114688
//                        within: mt(4)*4096 + kt(8)*512 + lane*8 + e
//  A2 A-frags (inv-h):   hi 131072, lo 163840
//                        within: mt(16)*2048 + kt(4)*512 + lane*8 + e
#define PK_E   0
#define PK_D   32768
#define PK_TF  65536
#define PK_A2  131072
#define PK_TOTAL 196608

// ---- fp32 -> bf16 split (hi + lo captures ~16 mantissa bits) ----
__device__ inline unsigned short f2bf(float f) {
    unsigned u = __float_as_uint(f);
    u += 0x7FFF + ((u >> 16) & 1);          // RNE
    return (unsigned short)(u >> 16);
}
__device__ inline void splitbf(float f, unsigned short& h, unsigned short& l) {
    unsigned short hh = f2bf(f);
    float fh = __uint_as_float(((unsigned)hh) << 16);
    l = f2bf(f - fh);
    h = hh;
}

// ---------------------------------------------------------------------------
// kprep: all twiddle tables, MFMA-fragment-packed, bf16 hi/lo.
// ---------------------------------------------------------------------------
__global__ void kprep(unsigned short* __restrict__ pk) {
    int id = blockIdx.x * 256 + threadIdx.x;    // 0..98303
    if (id < 16384) {
        // E (stage1 B-frag): n=2kx+c, k=w; val = c?-sin:cos(2pi w kx/256)
        int j = id & 7, lane = (id >> 3) & 63, nt = (id >> 9) & 3, kt = id >> 11;
        int k = kt * 32 + (lane >> 4) * 8 + j;
        int n = nt * 16 + (lane & 15);
        int kx = n >> 1, c = n & 1;
        int p = (k * kx) & 255;
        float sn, cs; sincosf(PI2 * (float)p / 256.0f, &sn, &cs);
        float val = c ? -sn : cs;
        unsigned short h, l; splitbf(val, h, l);
        pk[id] = h; pk[id + 16384] = l;
    } else if (id < 32768) {
        // D (stage5 B-frag): k=2kx+c, n=w; val = ck*(c?-sin:cos)(2pi kx w/256)
        int id2 = id - 16384;
        int j = id2 & 7, lane = (id2 >> 3) & 63, nt = (id2 >> 9) & 15, kt = id2 >> 13;
        int k = kt * 32 + (lane >> 4) * 8 + j;
        int w = nt * 16 + (lane & 15);
        int kx = k >> 1, c = k & 1;
        int p = (kx * w) & 255;
        float sn, cs; sincosf(PI2 * (float)p / 256.0f, &sn, &cs);
        float ck = (kx == 0) ? 1.0f : 2.0f;
        float val = c ? -ck * sn : ck * cs;
        unsigned short h, l; splitbf(val, h, l);
        pk[PK_D + id2] = h; pk[PK_D + 16384 + id2] = l;
    } else if (id < 65536) {
        // Tf (fwd-h A-frag): m=j, k=h; plane p: 0=cos,1=sin of 2pi ky h/256
        int idt = id - 32768;
        int e = idt & 7, lane = (idt >> 3) & 63, kt = (idt >> 9) & 7, mt = (idt >> 12) & 3, p = (idt >> 14) & 1;
        int j = mt * 16 + (lane & 15);
        int h = kt * 32 + (lane >> 4) * 8 + e;
        int ky = (j < 32) ? j : (192 + j);
        int ang = (ky * h) & 255;
        float sn, cs; sincosf(PI2 * (float)ang / 256.0f, &sn, &cs);
        float val = p ? sn : cs;
        unsigned short hh, ll; splitbf(val, hh, ll);
        int base = PK_TF + p * 32768 + mt * 4096 + kt * 512 + lane * 8 + e;
        pk[base] = hh; pk[base + 16384] = ll;
    } else {
        // A2 (inv-h A-frag): m=h, k'=kt*32+kq*8+e; j=k'&63, p=k'>>6
        int ida = id - 65536;
        int e = ida & 7, lane = (ida >> 3) & 63, kt = (ida >> 9) & 3, mt = ida >> 11;
        int h = mt * 16 + (lane & 15);
        int kp = kt * 32 + (lane >> 4) * 8 + e;
        int j = kp & 63, p = kp >> 6;
        int ky = (j < 32) ? j : (192 + j);
        int ang = (ky * h) & 255;
        float sn, cs; sincosf(PI2 * (float)ang / 256.0f, &sn, &cs);
        float val = p ? sn : cs;
        unsigned short hh, ll; splitbf(val, hh, ll);
        pk[PK_A2 + ida] = hh; pk[PK_A2 + 32768 + ida] = ll;
    }
}

// ---------------------------------------------------------------------------
// Stage W (MFMA): WC[s][m1m2][c][io] = dot(mlp_row, weights_row) over K=64
// ---------------------------------------------------------------------------
__global__ __launch_bounds__(256) void kweights(const float* __restrict__ wts,
                                                const float* __restrict__ mlp,
                                                float* __restrict__ WC) {
    int t = threadIdx.x;
    int wid = t >> 6, lane = t & 63;
    int bm = blockIdx.x >> 4, bn = blockIdx.x & 15;
    int m0 = bm * 128 + (wid >> 1) * 64;
    int n0 = bn * 128 + (wid & 1) * 64;
    int l15 = lane & 15, lq = lane >> 4;

    f32x4 acc[4][4];
    #pragma unroll
    for (int mt = 0; mt < 4; mt++)
        #pragma unroll
        for (int nt = 0; nt < 4; nt++)
            acc[mt][nt] = (f32x4){0.f, 0.f, 0.f, 0.f};

    #pragma unroll
    for (int kt = 0; kt < 2; kt++) {
        short8 Ah[4], Al[4];
        #pragma unroll
        for (int mt = 0; mt < 4; mt++) {
            int m = m0 + mt * 16 + l15;
            int c = m >> 10, mm = m & 1023;
            const float4* p = (const float4*)(mlp + (mm * 2 + c) * 64 + kt * 32 + lq * 8);
            float4 v0 = p[0], v1 = p[1];
            float vals[8] = {v0.x, v0.y, v0.z, v0.w, v1.x, v1.y, v1.z, v1.w};
            #pragma unroll
            for (int e = 0; e < 8; e++) {
                unsigned short h, l; splitbf(vals[e], h, l);
                Ah[mt][e] = (short)h; Al[mt][e] = (short)l;
            }
        }
        #pragma unroll
        for (int nt = 0; nt < 4; nt++) {
            int n = n0 + nt * 16 + l15;
            int s = n >> 10, io = n & 1023;
            const float4* p = (const float4*)(wts + (io * 2 + s) * 64 + kt * 32 + lq * 8);
            float4 v0 = p[0], v1 = p[1];
            float vals[8] = {v0.x, v0.y, v0.z, v0.w, v1.x, v1.y, v1.z, v1.w};
            short8 Bh, Bl;
            #pragma unroll
            for (int e = 0; e < 8; e++) {
                unsigned short h, l; splitbf(vals[e], h, l);
                Bh[e] = (short)h; Bl[e] = (short)l;
            }
            #pragma unroll
            for (int mt = 0; mt < 4; mt++) {
                acc[mt][nt] = __builtin_amdgcn_mfma_f32_16x16x32_bf16(Ah[mt], Bh, acc[mt][nt], 0, 0, 0);
                acc[mt][nt] = __builtin_amdgcn_mfma_f32_16x16x32_bf16(Ah[mt], Bl, acc[mt][nt], 0, 0, 0);
                acc[mt][nt] = __builtin_amdgcn_mfma_f32_16x16x32_bf16(Al[mt], Bh, acc[mt][nt], 0, 0, 0);
            }
        }
    }
    #pragma unroll
    for (int mt = 0; mt < 4; mt++)
        #pragma unroll
        for (int nt = 0; nt < 4; nt++)
            #pragma unroll
            for (int r = 0; r < 4; r++) {
                int m = m0 + mt * 16 + lq * 4 + r;
                int n = n0 + nt * 16 + l15;
                int addr = (((n >> 10) * 1024 + (m & 1023)) * 2 + (m >> 10)) * 1024 + (n & 1023);
                WC[addr] = acc[mt][nt][r];
            }
}

// ---------------------------------------------------------------------------
// kfwd (fused stages 1+2, all-MFMA): block = one (b,i) slab, 512 thr.
//  Stage 1: X[h][n] = x[h][:]*E  (MFMA), epilogue splits to bf16 hi/lo in LDS
//           as B-fragment layout [n][h] (stride 264).
//  Stage 2: C_A = cos*X, C_B = sin*X (MFMA, A-frags from pk); combine via
//           shfl_xor(1):  F_re(n even) = CA + CBsw, F_im(n odd) = CA - CBsw.
// ---------------------------------------------------------------------------
#define XS_STR 264
__global__ __launch_bounds__(512) void kfwd(const float* __restrict__ x,
                                            const unsigned short* __restrict__ pk,
                                            float* __restrict__ F) {
    __shared__ short Xbf[2][64 * XS_STR];   // 67.6 KB
    int t = threadIdx.x;
    int bi = blockIdx.x;
    int w = t >> 6, lane = t & 63;
    int l15 = lane & 15, lq = lane >> 4;

    // ---- stage 1: rows w*32 .. w*32+32 ----
    f32x4 acc[2][4];
    #pragma unroll
    for (int mt = 0; mt < 2; mt++)
        #pragma unroll
        for (int nt = 0; nt < 4; nt++)
            acc[mt][nt] = (f32x4){0.f, 0.f, 0.f, 0.f};

    #pragma unroll
    for (int kt = 0; kt < 8; kt++) {
        short8 bh[4], bl[4];
        #pragma unroll
        for (int nt = 0; nt < 4; nt++) {
            bh[nt] = *(const short8*)(pk + ((size_t)((kt * 4 + nt) * 64 + lane)) * 8);
            bl[nt] = *(const short8*)(pk + 16384 + ((size_t)((kt * 4 + nt) * 64 + lane)) * 8);
        }
        #pragma unroll
        for (int mt = 0; mt < 2; mt++) {
            const float4* ap = (const float4*)(x + (size_t)(bi * 256 + w * 32 + mt * 16 + l15) * 256 + kt * 32 + lq * 8);
            float4 v0 = ap[0], v1 = ap[1];
            float vals[8] = {v0.x, v0.y, v0.z, v0.w, v1.x, v1.y, v1.z, v1.w};
            short8 ah, al;
            #pragma unroll
            for (int e = 0; e < 8; e++) {
                unsigned short h, l; splitbf(vals[e], h, l);
                ah[e] = (short)h; al[e] = (short)l;
            }
            #pragma unroll
            for (int nt = 0; nt < 4; nt++) {
                acc[mt][nt] = __builtin_amdgcn_mfma_f32_16x16x32_bf16(ah, bh[nt], acc[mt][nt], 0, 0, 0);
                acc[mt][nt] = __builtin_amdgcn_mfma_f32_16x16x32_bf16(ah, bl[nt], acc[mt][nt], 0, 0, 0);
                acc[mt][nt] = __builtin_amdgcn_mfma_f32_16x16x32_bf16(al, bh[nt], acc[mt][nt], 0, 0, 0);
            }
        }
    }
    // epilogue: D-layout (row h = lq*4+r, col n = nt*16+l15) -> Xbf[n][h]
    #pragma unroll
    for (int mt = 0; mt < 2; mt++)
        #pragma unroll
        for (int nt = 0; nt < 4; nt++)
            #pragma unroll
            for (int r = 0; r < 4; r++) {
                int hrow = w * 32 + mt * 16 + lq * 4 + r;
                int n = nt * 16 + l15;
                unsigned short hh, ll; splitbf(acc[mt][nt][r], hh, ll);
                Xbf[0][n * XS_STR + hrow] = (short)hh;
                Xbf[1][n * XS_STR + hrow] = (short)ll;
            }
    __syncthreads();

    // ---- stage 2: wave w -> mtq = w>>1 (j-tile), ntbase = (w&1)*2 ----
    int mtq = w >> 1, ntbase = (w & 1) * 2;
    f32x4 ca[2], cb[2];
    ca[0] = (f32x4){0.f,0.f,0.f,0.f}; ca[1] = (f32x4){0.f,0.f,0.f,0.f};
    cb[0] = (f32x4){0.f,0.f,0.f,0.f}; cb[1] = (f32x4){0.f,0.f,0.f,0.f};
    #pragma unroll
    for (int kt = 0; kt < 8; kt++) {
        int aoff = PK_TF + mtq * 4096 + kt * 512 + lane * 8;
        short8 Ach = *(const short8*)(pk + aoff);
        short8 Acl = *(const short8*)(pk + aoff + 16384);
        short8 Ash = *(const short8*)(pk + aoff + 32768);
        short8 Asl = *(const short8*)(pk + aoff + 49152);
        #pragma unroll
        for (int ntl = 0; ntl < 2; ntl++) {
            int n = (ntbase + ntl) * 16 + l15;
            short8 xh = *(const short8*)&Xbf[0][n * XS_STR + kt * 32 + lq * 8];
            short8 xl = *(const short8*)&Xbf[1][n * XS_STR + kt * 32 + lq * 8];
            ca[ntl] = __builtin_amdgcn_mfma_f32_16x16x32_bf16(Ach, xh, ca[ntl], 0, 0, 0);
            ca[ntl] = __builtin_amdgcn_mfma_f32_16x16x32_bf16(Ach, xl, ca[ntl], 0, 0, 0);
            ca[ntl] = __builtin_amdgcn_mfma_f32_16x16x32_bf16(Acl, xh, ca[ntl], 0, 0, 0);
            cb[ntl] = __builtin_amdgcn_mfma_f32_16x16x32_bf16(Ash, xh, cb[ntl], 0, 0, 0);
            cb[ntl] = __builtin_amdgcn_mfma_f32_16x16x32_bf16(Ash, xl, cb[ntl], 0, 0, 0);
            cb[ntl] = __builtin_amdgcn_mfma_f32_16x16x32_bf16(Asl, xh, cb[ntl], 0, 0, 0);
        }
    }
    // combine + store: F_float[bi*4096 + j*64 + n]
    #pragma unroll
    for (int ntl = 0; ntl < 2; ntl++) {
        int n = (ntbase + ntl) * 16 + l15;
        #pragma unroll
        for (int r = 0; r < 4; r++) {
            float a = ca[ntl][r];
            float bsw = __shfl_xor(cb[ntl][r], 1, 64);
            float out = (n & 1) ? (a - bsw) : (a + bsw);
            int j = mtq * 16 + lq * 4 + r;
            F[(size_t)bi * 4096 + j * 64 + n] = out;
        }
    }
}

// ---------------------------------------------------------------------------
// Stage 3: mode mixing. WC layout [s][m1m2][c][io].
// ---------------------------------------------------------------------------
__global__ void kmodes(const float* __restrict__ F, const float* __restrict__ WC,
                       const float* __restrict__ mod1, const float* __restrict__ mod2,
                       float* __restrict__ OM) {
    int m = blockIdx.x;             // j*32 + kx
    int j = m >> 5, kx = m & 31;
    int s = j >> 5;
    int m1 = j & 31, m2 = kx;
    __shared__ float2 fs[BB][CI];
    __shared__ float wcr[CI * CO];
    __shared__ float wci[CI * CO];
    int t = threadIdx.x;
    {
        int b = t >> 5, i = t & 31;
        fs[b][i] = ((const float2*)F)[((size_t)(b * CI + i) * NJ + j) * KX + kx];
    }
    {
        const float4* wg = (const float4*)(WC + ((size_t)(s * 1024 + m1 * 32 + m2) * 2) * 1024);
        ((float4*)wcr)[t] = wg[t];
        ((float4*)wci)[t] = wg[t + 256];
    }
    __syncthreads();
    int b = t >> 5, o = t & 31;
    float ar = 0.f, ai = 0.f;
    #pragma unroll 8
    for (int i = 0; i < CI; i++) {
        float2 f = fs[b][i];
        float wx = wcr[i * 32 + o];
        float wy = wci[i * 32 + o];
        ar = fmaf(f.x, wx, ar);
        ar = fmaf(-f.y, wy, ar);
        ai = fmaf(f.x, wy, ai);
        ai = fmaf(f.y, wx, ai);
    }
    const float* mp = (s == 0) ? mod1 : mod2;
    float mr = mp[(b * 1024 + m1 * 32 + m2) * 2 + 0];
    float mi = mp[(b * 1024 + m1 * 32 + m2) * 2 + 1];
    const float scale = 1.0f / 65536.0f;
    float outr = (ar * mr - ai * mi) * scale;
    float outi = (ar * mi + ai * mr) * scale;
    ((float2*)OM)[((size_t)(b * CO + o) * NJ + j) * KX + kx] = make_float2(outr, outi);
}

// ---------------------------------------------------------------------------
// kinv (fused stages 4+5, all-MFMA): block = one (b,o) slab, 512 thr.
//  Phase 0: OM -> B' in LDS: B'[n=2kx+c][k'=p*64+j] (stride 136), hi/lo:
//           [2kx][j]=Or  [2kx][64+j]=-Oi  [2kx+1][j]=Oi  [2kx+1][64+j]=Or
//  Phase 1: G[h][n] = A2[h][:] * B'  (A2 = [cos|sin] frags from pk), M=256.
//  Phase 2: G -> LDS bf16 hi/lo as A-frag layout [h][n] (stride 72).
//  Phase 3: y[h][:] = G[h][:] * D (B-frags from pk).
// ---------------------------------------------------------------------------
#define BP_STR 136
#define GB_STR 72
__global__ __launch_bounds__(512) void kinv(const float* __restrict__ OM,
                                            const unsigned short* __restrict__ pk,
                                            float* __restrict__ y) {
    __shared__ short smem[2 * 256 * GB_STR];    // 73.7 KB (union: B' then Gbf)
    short* Bp0 = smem;                 // [64][136]
    short* Bp1 = smem + 64 * BP_STR;
    short* G0 = smem;                  // [256][72]
    short* G1 = smem + 256 * GB_STR;
    int t = threadIdx.x;
    int bo = blockIdx.x;
    int lane = t & 63, w = t >> 6;
    int l15 = lane & 15, lq = lane >> 4;

    // ---- phase 0: build B' ----
    {
        const float4* src = (const float4*)OM + (size_t)bo * 1024;
        #pragma unroll
        for (int q = 0; q < 2; q++) {
            int idx4 = t + q * 512;            // entry pair (2*idx4, 2*idx4+1)
            float4 v = src[idx4];
            #pragma unroll
            for (int half = 0; half < 2; half++) {
                int e = idx4 * 2 + half;
                int j = e >> 5, kx = e & 31;
                float Or = half ? v.z : v.x;
                float Oi = half ? v.w : v.y;
                unsigned short orh, orl, oih, oil, nih, nil;
                splitbf(Or, orh, orl);
                splitbf(Oi, oih, oil);
                splitbf(-Oi, nih, nil);
                Bp0[(2 * kx) * BP_STR + j] = (short)orh;      Bp1[(2 * kx) * BP_STR + j] = (short)orl;
                Bp0[(2 * kx) * BP_STR + 64 + j] = (short)nih; Bp1[(2 * kx) * BP_STR + 64 + j] = (short)nil;
                Bp0[(2 * kx + 1) * BP_STR + j] = (short)oih;  Bp1[(2 * kx + 1) * BP_STR + j] = (short)oil;
                Bp0[(2 * kx + 1) * BP_STR + 64 + j] = (short)orh; Bp1[(2 * kx + 1) * BP_STR + 64 + j] = (short)orl;
            }
        }
    }
    __syncthreads();

    // ---- phase 1: G = A2 * B', wave w -> mt = w*2+{0,1}, all 4 nt ----
    f32x4 g[2][4];
    #pragma unroll
    for (int mtl = 0; mtl < 2; mtl++)
        #pragma unroll
        for (int nt = 0; nt < 4; nt++)
            g[mtl][nt] = (f32x4){0.f, 0.f, 0.f, 0.f};
    #pragma unroll
    for (int kt = 0; kt < 4; kt++) {
        short8 a2h[2], a2l[2];
        #pragma unroll
        for (int mtl = 0; mtl < 2; mtl++) {
            int mt = w * 2 + mtl;
            int aoff = PK_A2 + mt * 2048 + kt * 512 + lane * 8;
            a2h[mtl] = *(const short8*)(pk + aoff);
            a2l[mtl] = *(const short8*)(pk + aoff + 32768);
        }
        #pragma unroll
        for (int nt = 0; nt < 4; nt++) {
            int n = nt * 16 + l15;
            short8 bh = *(const short8*)&Bp0[n * BP_STR + kt * 32 + lq * 8];
            short8 bl = *(const short8*)&Bp1[n * BP_STR + kt * 32 + lq * 8];
            #pragma unroll
            for (int mtl = 0; mtl < 2; mtl++) {
                g[mtl][nt] = __builtin_amdgcn_mfma_f32_16x16x32_bf16(a2h[mtl], bh, g[mtl][nt], 0, 0, 0);
                g[mtl][nt] = __builtin_amdgcn_mfma_f32_16x16x32_bf16(a2h[mtl], bl, g[mtl][nt], 0, 0, 0);
                g[mtl][nt] = __builtin_amdgcn_mfma_f32_16x16x32_bf16(a2l[mtl], bh, g[mtl][nt], 0, 0, 0);
            }
        }
    }
    __syncthreads();    // all B' reads done; smem becomes Gbf

    // ---- phase 2: store G as bf16 hi/lo, layout [h][n] ----
    #pragma unroll
    for (int mtl = 0; mtl < 2; mtl++)
        #pragma unroll
        for (int nt = 0; nt < 4; nt++)
            #pragma unroll
            for (int r = 0; r < 4; r++) {
                int h = (w * 2 + mtl) * 16 + lq * 4 + r;
                int n = nt * 16 + l15;
                unsigned short hh, ll; splitbf(g[mtl][nt][r], hh, ll);
                G0[h * GB_STR + n] = (short)hh;
                G1[h * GB_STR + n] = (short)ll;
            }
    __syncthreads();

    // ---- phase 3: y = G * D, wave w -> cols nt2 = w*2+{0,1} ----
    const unsigned short* pkD = pk + PK_D;
    short8 Bh[2][2], Bl[2][2];
    #pragma unroll
    for (int kt = 0; kt < 2; kt++)
        #pragma unroll
        for (int ntl = 0; ntl < 2; ntl++) {
            int nt = w * 2 + ntl;
            Bh[kt][ntl] = *(const short8*)(pkD + ((size_t)((kt * 16 + nt) * 64 + lane)) * 8);
            Bl[kt][ntl] = *(const short8*)(pkD + 16384 + ((size_t)((kt * 16 + nt) * 64 + lane)) * 8);
        }
    #pragma unroll 4
    for (int mt = 0; mt < 16; mt++) {
        f32x4 acc2[2];
        acc2[0] = (f32x4){0.f, 0.f, 0.f, 0.f};
        acc2[1] = (f32x4){0.f, 0.f, 0.f, 0.f};
        #pragma unroll
        for (int kt = 0; kt < 2; kt++) {
            short8 ah = *(const short8*)&G0[(mt * 16 + l15) * GB_STR + kt * 32 + lq * 8];
            short8 al = *(const short8*)&G1[(mt * 16 + l15) * GB_STR + kt * 32 + lq * 8];
            #pragma unroll
            for (int ntl = 0; ntl < 2; ntl++) {
                acc2[ntl] = __builtin_amdgcn_mfma_f32_16x16x32_bf16(ah, Bh[kt][ntl], acc2[ntl], 0, 0, 0);
                acc2[ntl] = __builtin_amdgcn_mfma_f32_16x16x32_bf16(ah, Bl[kt][ntl], acc2[ntl], 0, 0, 0);
                acc2[ntl] = __builtin_amdgcn_mfma_f32_16x16x32_bf16(al, Bh[kt][ntl], acc2[ntl], 0, 0, 0);
            }
        }
        #pragma unroll
        for (int ntl = 0; ntl < 2; ntl++)
            #pragma unroll
            for (int r = 0; r < 4; r++)
                y[(size_t)(bo * 256 + mt * 16 + lq * 4 + r) * 256 + (w * 2 + ntl) * 16 + l15] = acc2[ntl][r];
    }
}

// ---------------------------------------------------------------------------
extern "C" void kernel_launch(void* const* d_in, const int* in_sizes, int n_in,
                              void* d_out, int out_size, void* d_ws, size_t ws_size,
                              hipStream_t stream) {
    const float* x    = (const float*)d_in[0];
    const float* mod1 = (const float*)d_in[1];
    const float* mod2 = (const float*)d_in[2];
    const float* wts  = (const float*)d_in[3];
    const float* mlp  = (const float*)d_in[4];
    float* y = (float*)d_out;

    float* ws = (float*)d_ws;
    float* F  = ws;                         // 1,048,576 floats
    float* WC = F + 1048576;                // 4,194,304
    float* OM = WC + 4194304;               // 1,048,576
    unsigned short* pk = (unsigned short*)(OM + 1048576);   // 196,608 ushorts

    kprep   <<<dim3(384),  dim3(256), 0, stream>>>(pk);
    kweights<<<dim3(256),  dim3(256), 0, stream>>>(wts, mlp, WC);
    kfwd    <<<dim3(BB * CI), dim3(512), 0, stream>>>(x, pk, F);
    kmodes  <<<dim3(NJ * KX), dim3(256), 0, stream>>>(F, WC, mod1, mod2, OM);
    kinv    <<<dim3(BB * CO), dim3(512), 0, stream>>>(OM, pk, y);
}